// Round 1
// baseline (119.544 us; speedup 1.0000x reference)
//
#include <hip/hip_runtime.h>

#define NB 4096
#define NC 8192

// Compare-exchange on (key,payload) pairs: keep larger key in (ka,pa).
__device__ __forceinline__ void ce_pair(unsigned &ka, unsigned &pa,
                                        unsigned &kb, unsigned &pb) {
  bool sw = kb > ka;
  unsigned tk = sw ? kb : ka, tp = sw ? pb : pa;
  unsigned uk = sw ? ka : kb, up = sw ? pa : pb;
  ka = tk; pa = tp; kb = uk; pb = up;
}

// One wave (64 lanes) per (row, matrix). Streams the row, computes:
//  - bce row sum (conf-weighted)
//  - top-6 (by score) with target bit -> first-2-negatives bce sum + count
__global__ __launch_bounds__(256) void row_stats(
    const float* __restrict__ tk_s, const float* __restrict__ g_s,
    const float* __restrict__ tk_t, const float* __restrict__ g_t,
    const float* __restrict__ conf, float* __restrict__ ws) {
  const int lane = threadIdx.x & 63;
  const int wave = threadIdx.x >> 6;
  const int row  = (blockIdx.x << 2) + wave;
  const int mat  = blockIdx.y;

  const float4* S4 = reinterpret_cast<const float4*>(
      (mat ? g_s : tk_s) + (size_t)row * NC);
  const float4* T4 = reinterpret_cast<const float4*>(
      (mat ? g_t : tk_t) + (size_t)row * NC);

  // per-lane top-6, sorted desc by key (f32 score bits; scores>0 so monotonic)
  unsigned k0=0,k1=0,k2=0,k3=0,k4=0,k5=0;
  unsigned p0=0,p1=0,p2=0,p3=0,p4=0,p5=0;
  float bsum = 0.0f;  // sum of log(arg); bce_row_sum = -bsum

#define PROC(pv, tv, colv) {                                              \
    float p_ = (pv);                                                      \
    bool pos_ = (tv) > 0.5f;                                              \
    float arg_ = pos_ ? p_ : (1.0f - p_);                                 \
    bsum += __logf(arg_);                                                 \
    unsigned nk_ = __float_as_uint(p_);                                   \
    if (nk_ > k5) {                                                       \
      k5 = nk_; p5 = ((unsigned)(colv) << 1) | (pos_ ? 1u : 0u);          \
      ce_pair(k4,p4,k5,p5); ce_pair(k3,p3,k4,p4); ce_pair(k2,p2,k3,p3);   \
      ce_pair(k1,p1,k2,p2); ce_pair(k0,p0,k1,p1);                         \
    }                                                                     \
  }

  for (int i = 0; i < NC / 4 / 64; ++i) {   // 32 iters
    int v = i * 64 + lane;
    float4 s = S4[v];
    float4 t = T4[v];
    int c0 = v * 4;
    PROC(s.x, t.x, c0);
    PROC(s.y, t.y, c0 + 1);
    PROC(s.z, t.z, c0 + 2);
    PROC(s.w, t.w, c0 + 3);
  }
#undef PROC

  // wave-reduce bce sum (butterfly)
  #pragma unroll
  for (int off = 32; off > 0; off >>= 1) bsum += __shfl_xor(bsum, off);

  // wave-reduce top-6: butterfly merge; top-6 of two desc 6-lists =
  // bitonic-sort( max(L[i], P[5-i]) ), 7-CE network (pads fold away).
  #pragma unroll
  for (int off = 1; off < 64; off <<= 1) {
    unsigned q0=__shfl_xor(k0,off), q1=__shfl_xor(k1,off), q2=__shfl_xor(k2,off),
             q3=__shfl_xor(k3,off), q4=__shfl_xor(k4,off), q5=__shfl_xor(k5,off);
    unsigned r0=__shfl_xor(p0,off), r1=__shfl_xor(p1,off), r2=__shfl_xor(p2,off),
             r3=__shfl_xor(p3,off), r4=__shfl_xor(p4,off), r5=__shfl_xor(p5,off);
    bool c;
    unsigned m0k,m0p,m1k,m1p,m2k,m2p,m3k,m3p,m4k,m4p,m5k,m5p;
    c = q5 > k0; m0k = c?q5:k0; m0p = c?r5:p0;
    c = q4 > k1; m1k = c?q4:k1; m1p = c?r4:p1;
    c = q3 > k2; m2k = c?q3:k2; m2p = c?r3:p2;
    c = q2 > k3; m3k = c?q2:k3; m3p = c?r2:p3;
    c = q1 > k4; m4k = c?q1:k4; m4p = c?r1:p4;
    c = q0 > k5; m5k = c?q0:k5; m5p = c?r0:p5;
    // bitonic merge (desc), stages A,B,C with +inf pads removed:
    ce_pair(m0k,m0p,m4k,m4p); ce_pair(m1k,m1p,m5k,m5p);   // A
    ce_pair(m2k,m2p,m4k,m4p); ce_pair(m3k,m3p,m5k,m5p);   // B
    ce_pair(m0k,m0p,m1k,m1p); ce_pair(m2k,m2p,m3k,m3p);   // C
    ce_pair(m4k,m4p,m5k,m5p);
    k0=m0k;p0=m0p;k1=m1k;p1=m1p;k2=m2k;p2=m2p;
    k3=m3k;p3=m3p;k4=m4k;p4=m4p;k5=m5k;p5=m5p;
  }

  if (lane == 0) {
    // first <=2 negatives (target bit 0) in descending score order
    float nsum = 0.0f; int cnt = 0;
#define SELN(ki,pi) { if (((pi) & 1u) == 0u && cnt < 2) {                  \
      nsum += -__logf(1.0f - __uint_as_float(ki)); cnt++; } }
    SELN(k0,p0) SELN(k1,p1) SELN(k2,p2) SELN(k3,p3) SELN(k4,p4) SELN(k5,p5)
#undef SELN
    const int base = mat * NB + row;
    ws[base]            = conf[row] * (-bsum);  // conf-weighted bce row sum
    ws[2 * NB + base]   = nsum;                 // hard-negative bce sum
    ws[4 * NB + base]   = (float)cnt;           // hard-negative count
  }
}

// Deterministic single-block reduction + final loss math.
__global__ __launch_bounds__(256) void finalize_loss(
    const float* __restrict__ ws, float* __restrict__ out) {
  __shared__ float red[6][256];
  const int t = threadIdx.x;
  float a[6] = {0.f, 0.f, 0.f, 0.f, 0.f, 0.f};
  for (int r = t; r < NB; r += 256) {
    #pragma unroll
    for (int j = 0; j < 6; ++j) a[j] += ws[j * NB + r];
  }
  #pragma unroll
  for (int j = 0; j < 6; ++j) red[j][t] = a[j];
  __syncthreads();
  for (int s = 128; s > 0; s >>= 1) {
    if (t < s) {
      #pragma unroll
      for (int j = 0; j < 6; ++j) red[j][t] += red[j][t + s];
    }
    __syncthreads();
  }
  if (t == 0) {
    const float inv = 1.0f / ((float)NB * (float)NC);
    float tk = red[0][0] * inv + 0.5f * (red[2][0] / (red[4][0] + 1e-8f));
    float g  = red[1][0] * inv + 0.5f * (red[3][0] / (red[5][0] + 1e-8f));
    out[0] = 0.6f * tk + 0.4f * g;
    out[1] = tk;
    out[2] = g;
  }
}

extern "C" void kernel_launch(void* const* d_in, const int* in_sizes, int n_in,
                              void* d_out, int out_size, void* d_ws, size_t ws_size,
                              hipStream_t stream) {
  const float* tk_s = (const float*)d_in[0];
  const float* g_s  = (const float*)d_in[1];
  const float* tk_t = (const float*)d_in[2];
  const float* g_t  = (const float*)d_in[3];
  const float* conf = (const float*)d_in[4];
  float* ws  = (float*)d_ws;   // 6*NB floats = 96 KB
  float* out = (float*)d_out;  // 3 floats: total, tk_loss, g_loss

  dim3 grid(NB / 4, 2);        // 4 rows per block (one per wave), 2 matrices
  row_stats<<<grid, 256, 0, stream>>>(tk_s, g_s, tk_t, g_t, conf, ws);
  finalize_loss<<<1, 256, 0, stream>>>(ws, out);
}

// Round 2
// 109.368 us; speedup vs baseline: 1.0930x; 1.0930x over previous
//
#include <hip/hip_runtime.h>

#define NB 4096
#define NC 8192

// One wave (64 lanes) per (row, matrix). Streams the row computing:
//  - conf-weighted BCE row sum
//  - wave-SHARED top-6 (by score) with target bit, maintained uniformly:
//    ballot against exact running 6th-max threshold -> serial readlane
//    inserts under wave-uniform branches (no EXEC divergence, scalar-friendly).
__global__ __launch_bounds__(256) void row_stats(
    const float* __restrict__ tk_s, const float* __restrict__ g_s,
    const float* __restrict__ tk_t, const float* __restrict__ g_t,
    const float* __restrict__ conf, float* __restrict__ ws) {
  const int lane = threadIdx.x & 63;
  const int wave = threadIdx.x >> 6;
  const int row  = (blockIdx.x << 2) + wave;
  const int mat  = blockIdx.y;

  const float4* S4 = reinterpret_cast<const float4*>(
      (mat ? g_s : tk_s) + (size_t)row * NC);
  const float4* T4 = reinterpret_cast<const float4*>(
      (mat ? g_t : tk_t) + (size_t)row * NC);

  // wave-uniform shared top-6 (desc). keys = f32 bits (scores>0 -> monotonic).
  unsigned lk0=0,lk1=0,lk2=0,lk3=0,lk4=0,lk5=0;
  unsigned lp0=0,lp1=0,lp2=0,lp3=0,lp4=0,lp5=0;
  float bsum = 0.0f;            // sum of log(arg); bce_row_sum = -bsum
  unsigned tseed;               // (lower bound on row 6th-max) - 1

  // ---- load iter 0 + seed threshold from it ----
  float4 s = S4[lane];
  float4 t = T4[lane];
  {
    float m4 = fmaxf(fmaxf(s.x, s.y), fmaxf(s.z, s.w));
    // group-of-8 max (8 disjoint groups -> 8 distinct elements)
    m4 = fmaxf(m4, __shfl_xor(m4, 1));
    m4 = fmaxf(m4, __shfl_xor(m4, 2));
    m4 = fmaxf(m4, __shfl_xor(m4, 4));
    // min over the 8 group-maxes: provable lower bound on row 8th<=6th max
    m4 = fminf(m4, __shfl_xor(m4, 8));
    m4 = fminf(m4, __shfl_xor(m4, 16));
    m4 = fminf(m4, __shfl_xor(m4, 32));
    tseed = __float_as_uint(m4) - 1u;  // admit equality under strict >
  }

#define INS(KJ, PJ) { if (ck_ > KJ) { unsigned tk_ = KJ, tp_ = PJ;        \
    KJ = ck_; PJ = cp_; ck_ = tk_; cp_ = tp_; } }

  auto process = [&](float4 sv, float4 tv, int i) {
#define ELEM(se, te, e) {                                                 \
    float p_ = (se);                                                      \
    bool pos_ = (te) > 0.5f;                                              \
    float arg_ = pos_ ? p_ : (1.0f - p_);                                 \
    bsum += __logf(arg_);                                                 \
    unsigned kb_ = __float_as_uint(p_);                                   \
    unsigned thr_ = lk5 > tseed ? lk5 : tseed;                            \
    unsigned long long m_ = __ballot(kb_ > thr_);                         \
    if (m_) {                                                             \
      unsigned long long pm_ = __ballot(pos_);                            \
      do {                                                                \
        int l_ = __ffsll(m_) - 1;                                         \
        m_ &= m_ - 1;                                                     \
        unsigned key_ = __builtin_amdgcn_readlane(kb_, l_);               \
        if (key_ > lk5) {                                                 \
          unsigned ck_ = key_;                                            \
          unsigned cp_ = ((unsigned)(((i) * 64 + l_) * 4 + (e)) << 1) |   \
                         (unsigned)((pm_ >> l_) & 1ull);                  \
          INS(lk0, lp0) INS(lk1, lp1) INS(lk2, lp2)                       \
          INS(lk3, lp3) INS(lk4, lp4) INS(lk5, lp5)                       \
        }                                                                 \
      } while (m_);                                                       \
    }                                                                     \
  }
    ELEM(sv.x, tv.x, 0)
    ELEM(sv.y, tv.y, 1)
    ELEM(sv.z, tv.z, 2)
    ELEM(sv.w, tv.w, 3)
#undef ELEM
  };

  // ---- main loop, loads pipelined one iteration ahead ----
  for (int i = 0; i < 31; ++i) {
    float4 sn = S4[(i + 1) * 64 + lane];
    float4 tn = T4[(i + 1) * 64 + lane];
    process(s, t, i);
    s = sn; t = tn;
  }
  process(s, t, 31);
#undef INS

  // wave-reduce bce sum (butterfly)
  #pragma unroll
  for (int off = 32; off > 0; off >>= 1) bsum += __shfl_xor(bsum, off);

  if (lane == 0) {
    // first <=2 negatives (target bit 0) in descending score order
    float nsum = 0.0f; int cnt = 0;
#define SELN(ki, pi) { if (((pi) & 1u) == 0u && cnt < 2) {                \
      nsum += -__logf(1.0f - __uint_as_float(ki)); cnt++; } }
    SELN(lk0, lp0) SELN(lk1, lp1) SELN(lk2, lp2)
    SELN(lk3, lp3) SELN(lk4, lp4) SELN(lk5, lp5)
#undef SELN
    const int base = mat * NB + row;
    ws[base]          = conf[row] * (-bsum);  // conf-weighted bce row sum
    ws[2 * NB + base] = nsum;                 // hard-negative bce sum
    ws[4 * NB + base] = (float)cnt;           // hard-negative count
  }
}

// Deterministic single-block reduction + final loss math.
__global__ __launch_bounds__(256) void finalize_loss(
    const float* __restrict__ ws, float* __restrict__ out) {
  __shared__ float red[6][256];
  const int t = threadIdx.x;
  float a[6] = {0.f, 0.f, 0.f, 0.f, 0.f, 0.f};
  for (int r = t; r < NB; r += 256) {
    #pragma unroll
    for (int j = 0; j < 6; ++j) a[j] += ws[j * NB + r];
  }
  #pragma unroll
  for (int j = 0; j < 6; ++j) red[j][t] = a[j];
  __syncthreads();
  for (int s = 128; s > 0; s >>= 1) {
    if (t < s) {
      #pragma unroll
      for (int j = 0; j < 6; ++j) red[j][t] += red[j][t + s];
    }
    __syncthreads();
  }
  if (t == 0) {
    const float inv = 1.0f / ((float)NB * (float)NC);
    float tk = red[0][0] * inv + 0.5f * (red[2][0] / (red[4][0] + 1e-8f));
    float g  = red[1][0] * inv + 0.5f * (red[3][0] / (red[5][0] + 1e-8f));
    out[0] = 0.6f * tk + 0.4f * g;
    out[1] = tk;
    out[2] = g;
  }
}

extern "C" void kernel_launch(void* const* d_in, const int* in_sizes, int n_in,
                              void* d_out, int out_size, void* d_ws, size_t ws_size,
                              hipStream_t stream) {
  const float* tk_s = (const float*)d_in[0];
  const float* g_s  = (const float*)d_in[1];
  const float* tk_t = (const float*)d_in[2];
  const float* g_t  = (const float*)d_in[3];
  const float* conf = (const float*)d_in[4];
  float* ws  = (float*)d_ws;   // 6*NB floats = 96 KB
  float* out = (float*)d_out;  // 3 floats: total, tk_loss, g_loss

  dim3 grid(NB / 4, 2);        // 4 rows per block (one per wave), 2 matrices
  row_stats<<<grid, 256, 0, stream>>>(tk_s, g_s, tk_t, g_t, conf, ws);
  finalize_loss<<<1, 256, 0, stream>>>(ws, out);
}